// Round 12
// baseline (134.410 us; speedup 1.0000x reference)
//
#include <hip/hip_runtime.h>

// ArcMarginLoss fused: normalize -> MX-fp8 MFMA GEMM + fixed-max softmax -> NLL mean.
// N=8192, D=512, C=32000, scale=16, margin=0.2.
// R12: kill the TRANS pipe. R11 counters -> v_exp_f32 ~19cyc/wave64; 262M exps
// were the VALU wall (38us). Replace with Schraudolph fast-exp2 (fma+cvt+bitcast,
// 6cyc, zero-mean sawtooth +-4%): S error ~0.3% -> nll error ~0.003 << 0.276 thr.
// MFMA output is already log2-domain (acc = 16*log2e*cos), so fast-exp is direct.
// Exact-f32 label/margin path (k_lab + k_merge) untouched.

typedef __attribute__((ext_vector_type(4))) float f32x4;
typedef __attribute__((ext_vector_type(8))) int i32x8;

constexpr int N = 8192, D = 512, C = 32000;
constexpr int BM = 256;            // rows per block (4 waves x 4 tiles x 16 rows)
constexpr int GRP = 16;            // cols per chunk
constexpr int NSPLIT = 16;         // column splits of C
constexpr int CPS = C / NSPLIT;    // 2000 cols per split
constexpr int NCHUNK = CPS / GRP;  // 125 chunks
constexpr int KS = D / 128;        // 4 k-steps of K=128
constexpr float SCL = 16.0f;
constexpr float LOG2E = 1.4426950408889634f;
constexpr float COSM = 0.98006657784124163f;  // cos(0.2)
constexpr float SINM = 0.19866933079506122f;  // sin(0.2)
constexpr float EPSC = 1e-7f;
constexpr float EM16 = 1.12535174719259114e-07f;  // exp(-16)
constexpr int SCQ = 0x81818181;    // E8M0 byte 129 -> 2^2 per operand (2^4 total)
// Schraudolph: 2^y ~= bitcast_f32((uint)(y*2^23 + FEC)); FEC = (127-0.0574)*2^23
// tuned for ZERO-MEAN sawtooth error over uniform frac(y).
constexpr float FEC = 1064871712.0f;

// Pack 8 scaled floats -> 8 fp8 e4m3 bytes (two i32 words), hw RNE+sat.
__device__ __forceinline__ void pack8_fp8(const float* f, float sc, int& lo, int& hi) {
  lo = __builtin_amdgcn_cvt_pk_fp8_f32(f[0] * sc, f[1] * sc, 0, 0);
  lo = __builtin_amdgcn_cvt_pk_fp8_f32(f[2] * sc, f[3] * sc, lo, 1);
  hi = __builtin_amdgcn_cvt_pk_fp8_f32(f[4] * sc, f[5] * sc, 0, 0);
  hi = __builtin_amdgcn_cvt_pk_fp8_f32(f[6] * sc, f[7] * sc, hi, 1);
}

// x: one wave per row, L2-normalize, scale by log2e (MX scale supplies 2^4),
// emit row-major fp8 (8 B/lane). Also zero-inits the output scalar (block 0).
__global__ void k_norm_x(const float* __restrict__ in, char* __restrict__ out,
                         float* __restrict__ outz) {
  if (blockIdx.x == 0 && threadIdx.x == 0) *outz = 0.0f;
  int w = (blockIdx.x << 2) + (threadIdx.x >> 6);
  int lane = threadIdx.x & 63;
  const float* row = in + (size_t)w * D;
  float f[8];
  *(f32x4*)&f[0] = *(const f32x4*)(row + lane * 8);
  *(f32x4*)&f[4] = *(const f32x4*)(row + lane * 8 + 4);
  float ss = 0.f;
  #pragma unroll
  for (int i = 0; i < 8; ++i) ss += f[i] * f[i];
  #pragma unroll
  for (int m = 1; m <= 32; m <<= 1) ss += __shfl_xor(ss, m, 64);
  float sc = LOG2E / fmaxf(sqrtf(ss), 1e-12f);
  int lo, hi;
  pack8_fp8(f, sc, lo, hi);
  int2 pk; pk.x = lo; pk.y = hi;
  *(int2*)(out + (size_t)w * D + lane * 8) = pk;
}

// w: one block per 16-col group; normalize 16 rows, emit fused-ready layout.
// Per 8KB group: byte addr = ks*2048 + (g*16 + col)*32 + j holds
// w[col][ks*128 + g*32 + j] (j in 0..31): each fused lane's 32B is contiguous.
__global__ void k_normw_t(const float* __restrict__ in, char* __restrict__ wt) {
  __shared__ __align__(16) char lbuf[8192];
  const int tid = threadIdx.x, wv = tid >> 6, L = tid & 63;
  const int gidx = blockIdx.x;
  #pragma unroll
  for (int t = 0; t < 4; ++t) {
    int rl = t * 4 + wv;  // 0..15 (col within group)
    const float* row = in + ((size_t)gidx * 16 + rl) * D;
    float f[8];
    *(f32x4*)&f[0] = *(const f32x4*)(row + L * 8);
    *(f32x4*)&f[4] = *(const f32x4*)(row + L * 8 + 4);
    float ss = 0.f;
    #pragma unroll
    for (int i = 0; i < 8; ++i) ss += f[i] * f[i];
    #pragma unroll
    for (int m = 1; m <= 32; m <<= 1) ss += __shfl_xor(ss, m, 64);
    float sc = 1.0f / fmaxf(sqrtf(ss), 1e-12f);
    int lo, hi;
    pack8_fp8(f, sc, lo, hi);
    // lane L covers k in [8L,8L+8): ks=L>>4, g=(L>>2)&3, j0=(L&3)*8
    int addr = (L >> 4) * 2048 + (((L >> 2) & 3) * 16 + rl) * 32 + (L & 3) * 8;
    long pk = ((long)(unsigned)hi << 32) | (unsigned)lo;
    *(long*)(lbuf + addr) = pk;
  }
  __syncthreads();
  char* outp = wt + (size_t)gidx * 8192;
  #pragma unroll
  for (int i = 0; i < 2; ++i)
    *(uint4*)(outp + i * 4096 + tid * 16) = *(const uint4*)(lbuf + i * 4096 + tid * 16);
}

// Label-column cosine in f32 (one wave per row) -> coslab[N].
__global__ void k_lab(const float* __restrict__ x, const float* __restrict__ w,
                      const int* __restrict__ labels, float* __restrict__ coslab) {
  int r = (blockIdx.x << 2) + (threadIdx.x >> 6);
  int lane = threadIdx.x & 63;
  const float* xr = x + (size_t)r * D;
  const float* wr = w + (size_t)labels[r] * D;
  f32x4 a = *(const f32x4*)(xr + lane * 8);
  f32x4 b = *(const f32x4*)(xr + lane * 8 + 4);
  f32x4 p = *(const f32x4*)(wr + lane * 8);
  f32x4 q = *(const f32x4*)(wr + lane * 8 + 4);
  float xx = a.x*a.x + a.y*a.y + a.z*a.z + a.w*a.w + b.x*b.x + b.y*b.y + b.z*b.z + b.w*b.w;
  float ww = p.x*p.x + p.y*p.y + p.z*p.z + p.w*p.w + q.x*q.x + q.y*q.y + q.z*q.z + q.w*q.w;
  float xw = a.x*p.x + a.y*p.y + a.z*p.z + a.w*p.w + b.x*q.x + b.y*q.y + b.z*q.z + b.w*q.w;
  #pragma unroll
  for (int m = 1; m <= 32; m <<= 1) {
    xx += __shfl_xor(xx, m, 64);
    ww += __shfl_xor(ww, m, 64);
    xw += __shfl_xor(xw, m, 64);
  }
  if (lane == 0)
    coslab[r] = xw / (fmaxf(sqrtf(xx), 1e-12f) * fmaxf(sqrtf(ww), 1e-12f));
}

// One chunk: 16 MFMAs into ACC (ks=0 seeds from fzero), fast-exp2 epilogue of
// ACCPREV interleaved (fma+cvt+bitcast+add, no TRANS), staggered b refill.
#define CHUNK_STEP(ACC, ACCPREV, DOEXP, PNEXT)                                \
  {                                                                           \
    _Pragma("unroll")                                                         \
    for (int ks = 0; ks < KS; ++ks) {                                         \
      _Pragma("unroll")                                                       \
      for (int t = 0; t < 4; ++t)                                             \
        ACC[t] = __builtin_amdgcn_mfma_scale_f32_16x16x128_f8f6f4(            \
            af[t][ks], b[ks], ks == 0 ? fzero : ACC[t], 0, 0, 0,              \
            SCQ, 0, SCQ);                                                     \
      if (DOEXP) {                                                            \
        _Pragma("unroll")                                                     \
        for (int r = 0; r < 4; ++r)                                           \
          accS[ks][r] += __uint_as_float(                                     \
              (unsigned)fmaf(ACCPREV[ks][r], 8388608.0f, FEC));               \
      }                                                                       \
      b[ks] = *(const i32x8*)((PNEXT) + loff + ks * 2048);                    \
    }                                                                         \
  }

// Fused MX-fp8 GEMM, barrier-free, acc ping-pong; B streams L2->registers.
__global__ __launch_bounds__(256, 2) void k_fused(
    const char* __restrict__ xn8, const char* __restrict__ wt,
    float* __restrict__ pS) {
  const int tid = threadIdx.x;
  const int wv = tid >> 6, lane = tid & 63;
  const int g = lane >> 4, c = lane & 15;
  const int bid = blockIdx.x;
  const int logical = (bid & 7) * 64 + (bid >> 3);  // 512 = 8*64 XCD swizzle
  const int sp = logical >> 5;          // 0..15 (2 splits per XCD = 4MB in L2)
  const int rb = logical & 31;          // 0..31
  const int row0 = rb * BM + wv * 64;   // this wave's 64 rows (4 tiles of 16)

  // 4 A-tiles fully K-resident: af[t][ks] = x[row0+t*16+c][ks*128+g*32 .. +32].
  i32x8 af[4][KS];
  #pragma unroll
  for (int t = 0; t < 4; ++t) {
    const char* xr = xn8 + (size_t)(row0 + t * 16 + c) * D + g * 32;
    #pragma unroll
    for (int ks = 0; ks < KS; ++ks) af[t][ks] = *(const i32x8*)(xr + ks * 128);
  }

  float accS[4][4];
  #pragma unroll
  for (int t = 0; t < 4; ++t)
    #pragma unroll
    for (int r = 0; r < 4; ++r) accS[t][r] = 0.0f;

  const f32x4 fzero = (f32x4)0.0f;    // persistent zero C-in for ks=0

  // Wave-uniform chunk base p; per-lane offset loff (one VGPR, set once).
  const char* p = wt + (size_t)(sp * NCHUNK) * 8192;
  const int loff = lane * 32;

  i32x8 b[KS];
  #pragma unroll
  for (int ks = 0; ks < KS; ++ks) b[ks] = *(const i32x8*)(p + loff + ks * 2048);

  f32x4 accP[4], accQ[4];

  // Prologue: chunk 0 -> accP (no exps yet); refills b <- chunk 1.
  CHUNK_STEP(accP, accQ, false, p + 8192)

  for (int ch = 1; ch + 1 < NCHUNK; ch += 2) {
    // chunk ch -> accQ, exps of accP (chunk ch-1); refill b <- chunk ch+1.
    CHUNK_STEP(accQ, accP, true, p + 2 * 8192)
    // chunk ch+1 -> accP, exps of accQ (chunk ch); refill b <- chunk ch+2 (clamped).
    CHUNK_STEP(accP, accQ, true, (ch + 2 < NCHUNK ? p + 3 * 8192 : p + 2 * 8192))
    p += 2 * 8192;
  }
  // Tail: exps of accP (chunk 124).
  #pragma unroll
  for (int t = 0; t < 4; ++t)
    #pragma unroll
    for (int r = 0; r < 4; ++r)
      accS[t][r] += __uint_as_float((unsigned)fmaf(accP[t][r], 8388608.0f, FEC));

  // Sum over the 16 col-lanes of each group; write per-(row,split) partials.
  #pragma unroll
  for (int t = 0; t < 4; ++t)
    #pragma unroll
    for (int r = 0; r < 4; ++r) {
      float S = accS[t][r];
      #pragma unroll
      for (int m = 1; m <= 8; m <<= 1) S += __shfl_xor(S, m, 64);
      if (c == 0)
        pS[(size_t)sp * N + row0 + t * 16 + g * 4 + r] = S;
    }
}
#undef CHUNK_STEP

// Merge: S over splits (scaled by e^-16); swap plain label term for f32 margin
// term; NLL mean.
__global__ void k_merge(const float* __restrict__ pS, const float* __restrict__ coslab,
                        float* __restrict__ out) {
  int row = blockIdx.x * 256 + threadIdx.x;
  float S = 0.0f;
  #pragma unroll
  for (int s = 0; s < NSPLIT; ++s) S += pS[(size_t)s * N + row];
  float cl = coslab[row];
  float zp = SCL * cl;
  float ccl = fminf(fmaxf(cl, -1.0f + EPSC), 1.0f - EPSC);
  float zm = SCL * (ccl * COSM - sqrtf(1.0f - ccl * ccl) * SINM);
  float denom = S * EM16 - __expf(zp - SCL) + __expf(zm - SCL);
  float nll = SCL + logf(denom) - zm;
  #pragma unroll
  for (int m = 1; m <= 32; m <<= 1) nll += __shfl_xor(nll, m, 64);
  __shared__ float part[4];
  if ((threadIdx.x & 63) == 0) part[threadIdx.x >> 6] = nll;
  __syncthreads();
  if (threadIdx.x == 0)
    atomicAdd(out, (part[0] + part[1] + part[2] + part[3]) * (1.0f / N));
}

extern "C" void kernel_launch(void* const* d_in, const int* in_sizes, int n_in,
                              void* d_out, int out_size, void* d_ws, size_t ws_size,
                              hipStream_t stream) {
  const float* x = (const float*)d_in[0];
  const float* w = (const float*)d_in[1];
  const int* labels = (const int*)d_in[2];
  float* out = (float*)d_out;

  // ws: xn8 fp8 [N*D] | wt fp8-grouped [C*D] | pS f32 [NSPLIT*N] | coslab f32 [N]
  char* xn8 = (char*)d_ws;
  char* wt = xn8 + (size_t)N * D;
  float* pS = (float*)(wt + (size_t)C * D);
  float* coslab = pS + (size_t)NSPLIT * N;

  hipLaunchKernelGGL(k_norm_x, dim3(N / 4), dim3(256), 0, stream, x, xn8, out);
  hipLaunchKernelGGL(k_normw_t, dim3(C / 16), dim3(256), 0, stream, w, wt);
  hipLaunchKernelGGL(k_lab, dim3(N / 4), dim3(256), 0, stream, x, w, labels, coslab);
  hipLaunchKernelGGL(k_fused, dim3(32 * NSPLIT), dim3(256), 0, stream, xn8, wt, pS);
  hipLaunchKernelGGL(k_merge, dim3(N / 256), dim3(256), 0, stream, pS, coslab, out);
}